// Round 1
// baseline (44.234 us; speedup 1.0000x reference)
//
#include <hip/hip_runtime.h>

// h_t = tanh(x_t + 0.97*h_{t-1}), h_0 = 0, per row of shape (B=32, T=262144).
// Parallelized over time via contraction: |d h_t / d h_{t-1}| <= 0.97, so a
// chunk started W steps early from h=0 converges to the true state within
// 0.97^W (W=512 -> 1.7e-7, threshold is 2e-2).

#define T_LEN   262144
#define S_CHUNK 256
#define W_WARM  512
#define CPR     (T_LEN / S_CHUNK)   // 1024 chunks per row

__device__ __forceinline__ float vexp2f(float x) {
#if __has_builtin(__builtin_amdgcn_exp2f)
    return __builtin_amdgcn_exp2f(x);
#else
    float r; asm("v_exp_f32 %0, %1" : "=v"(r) : "v"(x)); return r;
#endif
}
__device__ __forceinline__ float vrcpf(float x) {
#if __has_builtin(__builtin_amdgcn_rcpf)
    return __builtin_amdgcn_rcpf(x);
#else
    float r; asm("v_rcp_f32 %0, %1" : "=v"(r) : "v"(x)); return r;
#endif
}

// Transformed recurrence. K = 2*log2(e), c = 0.97:
//   tanh(u) = 1 - 2*rcp(exp2(K*u) + 1)
//   state r_t = rcp(exp2(fma(A, r_{t-1}, b_t)) + 1),  A = -2*K*c
//   b_t = K*x_t + K*c   (off the dependent chain)
//   h_t = fma(-2, r_t, 1)  (off the dependent chain)
// h = 0  <=>  r = 0.5
__device__ __forceinline__ float step(float r, float b) {
    const float A = -2.0f * 2.8853900817779268f * 0.97f;
    return vrcpf(vexp2f(fmaf(A, r, b)) + 1.0f);
}

__global__ __launch_bounds__(64) void ipe_kernel(const float* __restrict__ x,
                                                 float* __restrict__ out) {
    const float K  = 2.8853900817779268f;   // 2*log2(e)
    const float Kc = K * 0.97f;

    int task  = blockIdx.x * 64 + threadIdx.x;
    int row   = task / CPR;
    int chunk = task - row * CPR;
    int p     = chunk * S_CHUNK;
    int start = p - W_WARM; if (start < 0) start = 0;

    const float4* __restrict__ xv =
        reinterpret_cast<const float4*>(x) + (size_t)row * (T_LEN / 4);
    float4* __restrict__ ov =
        reinterpret_cast<float4*>(out) + (size_t)row * (T_LEN / 4);

    int i  = start >> 2;          // current float4 group
    int pe = p >> 2;              // first body group
    int be = (p + S_CHUNK) >> 2;  // end group (exclusive)

    float r = 0.5f;

    // software pipeline, depth 2 (prefetch clamped so we never read past be-1)
    float4 va = xv[i];
    int i1 = i + 1; if (i1 > be - 1) i1 = be - 1;
    float4 vb = xv[i1];

    // ---- warm-up: advance state, no stores ----
    for (; i < pe; ++i) {
        int ip = i + 2; if (ip > be - 1) ip = be - 1;
        float4 vc = xv[ip];
        float b0 = fmaf(K, va.x, Kc);
        float b1 = fmaf(K, va.y, Kc);
        float b2 = fmaf(K, va.z, Kc);
        float b3 = fmaf(K, va.w, Kc);
        r = step(r, b0);
        r = step(r, b1);
        r = step(r, b2);
        r = step(r, b3);
        va = vb; vb = vc;
    }

    // ---- body: advance state and store outputs ----
    for (; i < be; ++i) {
        int ip = i + 2; if (ip > be - 1) ip = be - 1;
        float4 vc = xv[ip];
        float b0 = fmaf(K, va.x, Kc);
        float b1 = fmaf(K, va.y, Kc);
        float b2 = fmaf(K, va.z, Kc);
        float b3 = fmaf(K, va.w, Kc);
        float4 o;
        r = step(r, b0); o.x = fmaf(-2.0f, r, 1.0f);
        r = step(r, b1); o.y = fmaf(-2.0f, r, 1.0f);
        r = step(r, b2); o.z = fmaf(-2.0f, r, 1.0f);
        r = step(r, b3); o.w = fmaf(-2.0f, r, 1.0f);
        ov[i] = o;
        va = vb; vb = vc;
    }
}

extern "C" void kernel_launch(void* const* d_in, const int* in_sizes, int n_in,
                              void* d_out, int out_size, void* d_ws, size_t ws_size,
                              hipStream_t stream) {
    const float* x = (const float*)d_in[0];
    float* out = (float*)d_out;

    int B = in_sizes[0] / T_LEN;        // 32
    int tasks = B * CPR;                // 32768
    int blocks = tasks / 64;            // 512 workgroups of 1 wave each
    ipe_kernel<<<blocks, 64, 0, stream>>>(x, out);
}